// Round 9
// baseline (398.166 us; speedup 1.0000x reference)
//
#include <hip/hip_runtime.h>

// GCN 3-layer forward on gfx950.
// Round 9: gather restructured as half-wave edge-parallel. Lanes 0-31 process
// even edges, 32-63 odd edges; each lane covers 4 cols via dwordx2 -> one
// row-load instruction covers 2 edges (512B vs 256B), VMEM instrs per 4 edges
// 6 -> 3, 2 independent row loads in flight per lane. Cross-half __shfl
// reduction once per row; half-0 writes coalesced float4/uint2.

#define IN_CH 128

typedef __attribute__((ext_vector_type(8))) short bf16x8;
typedef __attribute__((ext_vector_type(4))) float f32x4;

__device__ inline unsigned short f2bf_rne(float f) {
    unsigned u = __float_as_uint(f);
    unsigned r = (u + 0x7FFFu + ((u >> 16) & 1u)) >> 16;
    return (unsigned short)r;
}
__device__ inline float bf2f(unsigned short h) {
    return __uint_as_float(((unsigned)h) << 16);
}
__device__ inline float bf2f_lo(unsigned m) {
    return __uint_as_float(m << 16);
}
__device__ inline float bf2f_hi(unsigned m) {
    return __uint_as_float(m & 0xffff0000u);
}

// ---------------- degree count ----------------
__global__ __launch_bounds__(256) void cnt_k(const int* __restrict__ dst,
                                             int* __restrict__ cnt, int E) {
    int e = blockIdx.x * 256 + threadIdx.x;
    if (e < E) atomicAdd(&cnt[dst[e]], 1);
}

// ---------------- scan stage 1 (+ dinv fused) ----------------
__global__ __launch_bounds__(256) void scan1_k(const int* __restrict__ cnt,
                                               int* __restrict__ bsum,
                                               float* __restrict__ dinv, int N) {
    __shared__ int s[256];
    int tid = threadIdx.x;
    int i = blockIdx.x * 256 + tid;
    int v = (i < N) ? cnt[i] : 0;
    if (i < N) dinv[i] = rsqrtf((float)v + 1.0f);
    s[tid] = v;
    __syncthreads();
    for (int off = 128; off > 0; off >>= 1) {
        if (tid < off) s[tid] += s[tid + off];
        __syncthreads();
    }
    if (tid == 0) bsum[blockIdx.x] = s[0];
}

__global__ __launch_bounds__(512) void scan2_k(int* __restrict__ bsum, int nb) {
    __shared__ int s[512];
    __shared__ int carry_s;
    int tid = threadIdx.x;
    if (tid == 0) carry_s = 0;
    __syncthreads();
    for (int base = 0; base < nb; base += 512) {
        int c = carry_s;
        int i = base + tid;
        int v = (i < nb) ? bsum[i] : 0;
        s[tid] = v;
        __syncthreads();
        for (int off = 1; off < 512; off <<= 1) {
            int t = (tid >= off) ? s[tid - off] : 0;
            __syncthreads();
            s[tid] += t;
            __syncthreads();
        }
        if (i < nb) bsum[i] = s[tid] - v + c;
        __syncthreads();
        if (tid == 0) carry_s = c + s[511];
        __syncthreads();
    }
}

__global__ __launch_bounds__(256) void scan3_k(const int* __restrict__ cnt,
                                               const int* __restrict__ bsum,
                                               int* __restrict__ rowptr, int N) {
    __shared__ int s[256];
    int tid = threadIdx.x;
    int i = blockIdx.x * 256 + tid;
    int v = (i < N) ? cnt[i] : 0;
    s[tid] = v;
    __syncthreads();
    for (int off = 1; off < 256; off <<= 1) {
        int t = (tid >= off) ? s[tid - off] : 0;
        __syncthreads();
        s[tid] += t;
        __syncthreads();
    }
    if (i < N) rowptr[i] = s[tid] - v + bsum[blockIdx.x];
}

// ---------------- fill (CSR pairs) + weight conversion, one launch ----------
__device__ inline void convw_one(const float* W, unsigned short* hi, int FOUT, int id) {
    int n = id >> 7, k = id & 127;
    hi[id] = f2bf_rne(W[k * FOUT + n]);
}

__global__ __launch_bounds__(256) void fill_conv_k(
    const int* __restrict__ src, const int* __restrict__ dst,
    const float* __restrict__ dinv, int* __restrict__ rowptr,
    int2* __restrict__ pairs, int E, int fillBlocks,
    const float* __restrict__ W1, const float* __restrict__ W2,
    const float* __restrict__ W3,
    unsigned short* __restrict__ W1h, unsigned short* __restrict__ W2h,
    unsigned short* __restrict__ W3h) {
    if ((int)blockIdx.x < fillBlocks) {
        int e = blockIdx.x * 256 + threadIdx.x;
        if (e < E) {
            int s = src[e], d = dst[e];
            float nrm = dinv[s] * dinv[d];
            int pos = atomicAdd(&rowptr[d], 1);
            pairs[pos] = make_int2(s, __float_as_int(nrm));
        }
    } else {
        int id = (blockIdx.x - fillBlocks) * 256 + threadIdx.x;
        if (id < 16384) convw_one(W1, W1h, 128, id);
        else if (id < 32768) convw_one(W2, W2h, 128, id - 16384);
        else if (id < 40960) convw_one(W3, W3h, 64, id - 32768);
    }
}

// ---------------- MFMA GEMM: T[N][FOUT] = A[N][128] @ W[128][FOUT] ----------
// C = (Ah+Al)*Bh, fp32 acc. Block = 4 waves x 16 rows = 64 rows. Bh staged in
// LDS once per block (R8: fixes per-wave B L2-latency chain). Stride 136.
__device__ inline void split8(const float* __restrict__ p, bf16x8& hi, bf16x8& lo) {
    float4 v0 = *(const float4*)p;
    float4 v1 = *(const float4*)(p + 4);
    float vv[8] = {v0.x, v0.y, v0.z, v0.w, v1.x, v1.y, v1.z, v1.w};
#pragma unroll
    for (int i = 0; i < 8; ++i) {
        unsigned short h = f2bf_rne(vv[i]);
        hi[i] = (short)h;
        lo[i] = (short)f2bf_rne(vv[i] - bf2f(h));
    }
}

template <int FOUT, bool AF32>
__global__ __launch_bounds__(256) void mfma_gemm(const float* __restrict__ Af,
                                                 const unsigned short* __restrict__ Ahi,
                                                 const unsigned short* __restrict__ Alo,
                                                 const unsigned short* __restrict__ Bhi,
                                                 unsigned short* __restrict__ Thi,
                                                 unsigned short* __restrict__ Tlo,
                                                 int N) {
    constexpr int NCT = FOUT / 16;
    constexpr int BSTRIDE = 136;
    __shared__ unsigned short Bs[FOUT * BSTRIDE];

    const int tid = threadIdx.x;
    const int wv = tid >> 6, lane = tid & 63;
    const int quad = lane >> 4, l16 = lane & 15;
    const int row0 = blockIdx.x * 64 + wv * 16;

#pragma unroll
    for (int it = 0; it < FOUT / 16; ++it) {
        int i = it * 256 + tid;
        int r = i >> 4, c = (i & 15) * 8;
        *(bf16x8*)(&Bs[r * BSTRIDE + c]) = *(const bf16x8*)(Bhi + (size_t)r * 128 + c);
    }
    __syncthreads();

    f32x4 acc[NCT];
#pragma unroll
    for (int ct = 0; ct < NCT; ++ct)
        acc[ct] = (f32x4){0.f, 0.f, 0.f, 0.f};

    const int ra = AF32 ? min(row0 + l16, N - 1) : (row0 + l16);

#pragma unroll
    for (int ks = 0; ks < 4; ++ks) {
        const int ko = ks * 32 + quad * 8;
        bf16x8 ah, al;
        if (AF32) {
            split8(Af + (size_t)ra * 128 + ko, ah, al);
        } else {
            ah = *(const bf16x8*)(Ahi + (size_t)ra * 128 + ko);
            al = *(const bf16x8*)(Alo + (size_t)ra * 128 + ko);
        }
#pragma unroll
        for (int ct = 0; ct < NCT; ++ct) {
            bf16x8 bh = *(const bf16x8*)(&Bs[(ct * 16 + l16) * BSTRIDE + ko]);
            acc[ct] = __builtin_amdgcn_mfma_f32_16x16x32_bf16(ah, bh, acc[ct], 0, 0, 0);
            acc[ct] = __builtin_amdgcn_mfma_f32_16x16x32_bf16(al, bh, acc[ct], 0, 0, 0);
        }
    }

    const int rbase = row0 + quad * 4;
#pragma unroll
    for (int ct = 0; ct < NCT; ++ct) {
        const int col = ct * 16 + l16;
        f32x4 v = acc[ct];
#pragma unroll
        for (int r = 0; r < 4; ++r) {
            if (rbase + r < N) {
                size_t idx = (size_t)(rbase + r) * FOUT + col;
                unsigned short h = f2bf_rne(v[r]);
                Thi[idx] = h;
                Tlo[idx] = f2bf_rne(v[r] - bf2f(h));
            }
        }
    }
}

// ---------------- aggregation: half-wave edge-parallel, no atomics ---------
// res[row] = b + (Thi+Tlo)[row]*dinv^2 + sum_e norm_e * Thi[src_e]
// Lanes 0-31 (half 0): even edges; 32-63 (half 1): odd edges. Each lane
// covers 4 cols (FOUT=128, dwordx2) or 2 cols (FOUT=64, dword). Cross-half
// __shfl(lane^32) reduce, half-0 stores.
template <int FOUT, bool SPLIT>
__global__ __launch_bounds__(256) void gather_k(const int* __restrict__ rowend,
                                                const int2* __restrict__ pairs,
                                                const float* __restrict__ dinv,
                                                const unsigned short* __restrict__ Thi,
                                                const unsigned short* __restrict__ Tlo,
                                                const float* __restrict__ bias,
                                                float* __restrict__ out,
                                                unsigned short* __restrict__ outHi,
                                                unsigned short* __restrict__ outLo,
                                                int N) {
    const int wave = threadIdx.x >> 6;
    const int lane = threadIdx.x & 63;
    const int half = lane >> 5;
    const int hl = lane & 31;
    const int row = blockIdx.x * 4 + wave;
    if (row >= N) return;

    const int start = (row == 0) ? 0 : rowend[row - 1];
    const int end = rowend[row];
    const float dr = dinv[row];
    const float dr2 = dr * dr;

    if (FOUT == 128) {
        const unsigned* thi32 = (const unsigned*)Thi;  // dword = 2 bf16 cols
        const unsigned* tlo32 = (const unsigned*)Tlo;
        const int c4 = hl * 4;       // 4 cols per lane
        const int cd = hl * 2;       // dword offset within row (64 dwords/row)

        float a0 = 0.f, a1 = 0.f, a2 = 0.f, a3 = 0.f;
        if (half == 0) {
            uint2 sh = *(const uint2*)(thi32 + (size_t)row * 64 + cd);
            uint2 sl = *(const uint2*)(tlo32 + (size_t)row * 64 + cd);
            float4 bb = *(const float4*)(bias + c4);
            a0 = bb.x + (bf2f_lo(sh.x) + bf2f_lo(sl.x)) * dr2;
            a1 = bb.y + (bf2f_hi(sh.x) + bf2f_hi(sl.x)) * dr2;
            a2 = bb.z + (bf2f_lo(sh.y) + bf2f_lo(sl.y)) * dr2;
            a3 = bb.w + (bf2f_hi(sh.y) + bf2f_hi(sl.y)) * dr2;
        }

        int j = start;
        if ((j & 1) && j < end) {  // head peel -> even j (int4 alignment)
            if (half == 0) {
                int2 pv = pairs[j];
                uint2 m = *(const uint2*)(thi32 + (size_t)pv.x * 64 + cd);
                float n = __int_as_float(pv.y);
                a0 += n * bf2f_lo(m.x); a1 += n * bf2f_hi(m.x);
                a2 += n * bf2f_lo(m.y); a3 += n * bf2f_hi(m.y);
            }
            ++j;
        }
        for (; j + 4 <= end; j += 4) {  // 4 edges/iter, 2 per half
            int4 pq = *(const int4*)(pairs + j + 2 * half);
            uint2 mA = *(const uint2*)(thi32 + (size_t)pq.x * 64 + cd);
            uint2 mB = *(const uint2*)(thi32 + (size_t)pq.z * 64 + cd);
            float nA = __int_as_float(pq.y), nB = __int_as_float(pq.w);
            a0 += nA * bf2f_lo(mA.x); a1 += nA * bf2f_hi(mA.x);
            a2 += nA * bf2f_lo(mA.y); a3 += nA * bf2f_hi(mA.y);
            a0 += nB * bf2f_lo(mB.x); a1 += nB * bf2f_hi(mB.x);
            a2 += nB * bf2f_lo(mB.y); a3 += nB * bf2f_hi(mB.y);
        }
        if (j + 2 <= end) {  // 2-edge tail: half h takes edge j+h
            int2 pv = pairs[j + half];
            uint2 m = *(const uint2*)(thi32 + (size_t)pv.x * 64 + cd);
            float n = __int_as_float(pv.y);
            a0 += n * bf2f_lo(m.x); a1 += n * bf2f_hi(m.x);
            a2 += n * bf2f_lo(m.y); a3 += n * bf2f_hi(m.y);
            j += 2;
        }
        if (j < end && half == 0) {  // 1-edge tail
            int2 pv = pairs[j];
            uint2 m = *(const uint2*)(thi32 + (size_t)pv.x * 64 + cd);
            float n = __int_as_float(pv.y);
            a0 += n * bf2f_lo(m.x); a1 += n * bf2f_hi(m.x);
            a2 += n * bf2f_lo(m.y); a3 += n * bf2f_hi(m.y);
        }

        // cross-half reduce
        a0 += __shfl(a0, lane ^ 32);
        a1 += __shfl(a1, lane ^ 32);
        a2 += __shfl(a2, lane ^ 32);
        a3 += __shfl(a3, lane ^ 32);

        if (half == 0) {
            if (SPLIT) {
                float v0 = fmaxf(a0, 0.f), v1 = fmaxf(a1, 0.f);
                float v2 = fmaxf(a2, 0.f), v3 = fmaxf(a3, 0.f);
                unsigned h0 = f2bf_rne(v0), h1 = f2bf_rne(v1);
                unsigned h2 = f2bf_rne(v2), h3 = f2bf_rne(v3);
                unsigned l0 = f2bf_rne(v0 - bf2f((unsigned short)h0));
                unsigned l1 = f2bf_rne(v1 - bf2f((unsigned short)h1));
                unsigned l2 = f2bf_rne(v2 - bf2f((unsigned short)h2));
                unsigned l3 = f2bf_rne(v3 - bf2f((unsigned short)h3));
                uint2 hw, lw;
                hw.x = h0 | (h1 << 16); hw.y = h2 | (h3 << 16);
                lw.x = l0 | (l1 << 16); lw.y = l2 | (l3 << 16);
                *(uint2*)(outHi + (size_t)row * 128 + c4) = hw;
                *(uint2*)(outLo + (size_t)row * 128 + c4) = lw;
            } else {
                float4 o; o.x = a0; o.y = a1; o.z = a2; o.w = a3;
                *(float4*)(out + (size_t)row * 128 + c4) = o;
            }
        }
    } else {  // FOUT == 64, fp32 out only
        const int c2 = hl * 2;  // 2 cols per lane
        float a0 = 0.f, a1 = 0.f;
        if (half == 0) {
            unsigned sh = *(const unsigned*)(Thi + (size_t)row * 64 + c2);
            unsigned sl = *(const unsigned*)(Tlo + (size_t)row * 64 + c2);
            float2 bb = *(const float2*)(bias + c2);
            a0 = bb.x + (bf2f_lo(sh) + bf2f_lo(sl)) * dr2;
            a1 = bb.y + (bf2f_hi(sh) + bf2f_hi(sl)) * dr2;
        }

        int j = start;
        if ((j & 1) && j < end) {
            if (half == 0) {
                int2 pv = pairs[j];
                unsigned m = *(const unsigned*)(Thi + (size_t)pv.x * 64 + c2);
                float n = __int_as_float(pv.y);
                a0 += n * bf2f_lo(m); a1 += n * bf2f_hi(m);
            }
            ++j;
        }
        for (; j + 4 <= end; j += 4) {
            int4 pq = *(const int4*)(pairs + j + 2 * half);
            unsigned mA = *(const unsigned*)(Thi + (size_t)pq.x * 64 + c2);
            unsigned mB = *(const unsigned*)(Thi + (size_t)pq.z * 64 + c2);
            float nA = __int_as_float(pq.y), nB = __int_as_float(pq.w);
            a0 += nA * bf2f_lo(mA); a1 += nA * bf2f_hi(mA);
            a0 += nB * bf2f_lo(mB); a1 += nB * bf2f_hi(mB);
        }
        if (j + 2 <= end) {
            int2 pv = pairs[j + half];
            unsigned m = *(const unsigned*)(Thi + (size_t)pv.x * 64 + c2);
            float n = __int_as_float(pv.y);
            a0 += n * bf2f_lo(m); a1 += n * bf2f_hi(m);
            j += 2;
        }
        if (j < end && half == 0) {
            int2 pv = pairs[j];
            unsigned m = *(const unsigned*)(Thi + (size_t)pv.x * 64 + c2);
            float n = __int_as_float(pv.y);
            a0 += n * bf2f_lo(m); a1 += n * bf2f_hi(m);
        }

        a0 += __shfl(a0, lane ^ 32);
        a1 += __shfl(a1, lane ^ 32);

        if (half == 0) {
            float2 o; o.x = a0; o.y = a1;
            *(float2*)(out + (size_t)row * 64 + c2) = o;
        }
    }
}

extern "C" void kernel_launch(void* const* d_in, const int* in_sizes, int n_in,
                              void* d_out, int out_size, void* d_ws, size_t ws_size,
                              hipStream_t stream) {
    const float* x  = (const float*)d_in[0];
    const int* eidx = (const int*)d_in[1];
    const float* W1 = (const float*)d_in[2];
    const float* b1 = (const float*)d_in[3];
    const float* W2 = (const float*)d_in[4];
    const float* b2 = (const float*)d_in[5];
    const float* W3 = (const float*)d_in[6];
    const float* b3 = (const float*)d_in[7];
    float* out = (float*)d_out;

    const int N = in_sizes[0] / IN_CH;
    const int E = in_sizes[1] / 2;
    const int* src = eidx;
    const int* dst = eidx + E;
    const int Npad = ((N + 127) / 128) * 128;
    const int nb = (N + 255) / 256;

    auto align = [](size_t v) { return (v + 255) / 256 * 256; };
    char* p = (char*)d_ws;
    int* cnt = (int*)p;            p += align((size_t)N * 4);
    int* rowptr = (int*)p;         p += align((size_t)N * 4);
    int* bsum = (int*)p;           p += align((size_t)nb * 4);
    float* dinv = (float*)p;       p += align((size_t)N * 4);
    int2* pairs = (int2*)p;        p += align((size_t)E * 8);
    unsigned short* Ahi = (unsigned short*)p;  p += align((size_t)Npad * 128 * 2);
    unsigned short* Alo = (unsigned short*)p;  p += align((size_t)Npad * 128 * 2);
    unsigned short* Thi = (unsigned short*)p;  p += align((size_t)Npad * 128 * 2);
    unsigned short* Tlo = (unsigned short*)p;  p += align((size_t)Npad * 128 * 2);
    unsigned short* W1h = (unsigned short*)p;  p += align(128 * 128 * 2);
    unsigned short* W2h = (unsigned short*)p;  p += align(128 * 128 * 2);
    unsigned short* W3h = (unsigned short*)p;

    // ---- CSR build (once; reused by all 3 layers) ----
    hipMemsetAsync(cnt, 0, (size_t)N * 4, stream);
    cnt_k<<<(E + 255) / 256, 256, 0, stream>>>(dst, cnt, E);
    scan1_k<<<nb, 256, 0, stream>>>(cnt, bsum, dinv, N);
    scan2_k<<<1, 512, 0, stream>>>(bsum, nb);
    scan3_k<<<nb, 256, 0, stream>>>(cnt, bsum, rowptr, N);
    const int fillBlocks = (E + 255) / 256;
    fill_conv_k<<<fillBlocks + 160, 256, 0, stream>>>(src, dst, dinv, rowptr, pairs,
                                                      E, fillBlocks, W1, W2, W3,
                                                      W1h, W2h, W3h);
    // rowptr[i] now holds END of row i.

    const int gemm_blocks = (N + 63) / 64;
    const int gather_blocks = (N + 3) / 4;

    // Layer 1 (A = x fp32, split in-register)
    mfma_gemm<128, true><<<gemm_blocks, 256, 0, stream>>>(x, nullptr, nullptr,
                                                          W1h, Thi, Tlo, N);
    gather_k<128, true><<<gather_blocks, 256, 0, stream>>>(rowptr, pairs, dinv, Thi, Tlo,
                                                           b1, nullptr, Ahi, Alo, N);
    // Layer 2
    mfma_gemm<128, false><<<gemm_blocks, 256, 0, stream>>>(nullptr, Ahi, Alo,
                                                           W2h, Thi, Tlo, N);
    gather_k<128, true><<<gather_blocks, 256, 0, stream>>>(rowptr, pairs, dinv, Thi, Tlo,
                                                           b2, nullptr, Ahi, Alo, N);
    // Layer 3
    mfma_gemm<64, false><<<gemm_blocks, 256, 0, stream>>>(nullptr, Ahi, Alo,
                                                          W3h, Thi, Tlo, N);
    gather_k<64, false><<<gather_blocks, 256, 0, stream>>>(rowptr, pairs, dinv, Thi, Tlo,
                                                           b3, out, nullptr, nullptr, N);
}

// Round 10
// 392.253 us; speedup vs baseline: 1.0151x; 1.0151x over previous
//
#include <hip/hip_runtime.h>

// GCN 3-layer forward on gfx950.
// Round 10: gather reverted to R8 form (R9 half-wave split regressed: same
// random-256B transaction count, more VALU). GEMM epilogue now LDS-staged:
// C hi+lo tiles staged in the Bs union buffer (stride FOUT+8, 16B-aligned
// rows), copied out as coalesced dwordx4 (8 wide stores/thread vs 64 scalar
// 2B stores). R6's failed attempt was confounded by B-refetch; B now in LDS.

#define IN_CH 128

typedef __attribute__((ext_vector_type(8))) short bf16x8;
typedef __attribute__((ext_vector_type(4))) float f32x4;

__device__ inline unsigned short f2bf_rne(float f) {
    unsigned u = __float_as_uint(f);
    unsigned r = (u + 0x7FFFu + ((u >> 16) & 1u)) >> 16;
    return (unsigned short)r;
}
__device__ inline float bf2f(unsigned short h) {
    return __uint_as_float(((unsigned)h) << 16);
}
__device__ inline float bf2f_lo(unsigned m) {
    return __uint_as_float(m << 16);
}
__device__ inline float bf2f_hi(unsigned m) {
    return __uint_as_float(m & 0xffff0000u);
}

// ---------------- degree count ----------------
__global__ __launch_bounds__(256) void cnt_k(const int* __restrict__ dst,
                                             int* __restrict__ cnt, int E) {
    int e = blockIdx.x * 256 + threadIdx.x;
    if (e < E) atomicAdd(&cnt[dst[e]], 1);
}

// ---------------- scan stage 1 (+ dinv fused) ----------------
__global__ __launch_bounds__(256) void scan1_k(const int* __restrict__ cnt,
                                               int* __restrict__ bsum,
                                               float* __restrict__ dinv, int N) {
    __shared__ int s[256];
    int tid = threadIdx.x;
    int i = blockIdx.x * 256 + tid;
    int v = (i < N) ? cnt[i] : 0;
    if (i < N) dinv[i] = rsqrtf((float)v + 1.0f);
    s[tid] = v;
    __syncthreads();
    for (int off = 128; off > 0; off >>= 1) {
        if (tid < off) s[tid] += s[tid + off];
        __syncthreads();
    }
    if (tid == 0) bsum[blockIdx.x] = s[0];
}

__global__ __launch_bounds__(512) void scan2_k(int* __restrict__ bsum, int nb) {
    __shared__ int s[512];
    __shared__ int carry_s;
    int tid = threadIdx.x;
    if (tid == 0) carry_s = 0;
    __syncthreads();
    for (int base = 0; base < nb; base += 512) {
        int c = carry_s;
        int i = base + tid;
        int v = (i < nb) ? bsum[i] : 0;
        s[tid] = v;
        __syncthreads();
        for (int off = 1; off < 512; off <<= 1) {
            int t = (tid >= off) ? s[tid - off] : 0;
            __syncthreads();
            s[tid] += t;
            __syncthreads();
        }
        if (i < nb) bsum[i] = s[tid] - v + c;
        __syncthreads();
        if (tid == 0) carry_s = c + s[511];
        __syncthreads();
    }
}

__global__ __launch_bounds__(256) void scan3_k(const int* __restrict__ cnt,
                                               const int* __restrict__ bsum,
                                               int* __restrict__ rowptr, int N) {
    __shared__ int s[256];
    int tid = threadIdx.x;
    int i = blockIdx.x * 256 + tid;
    int v = (i < N) ? cnt[i] : 0;
    s[tid] = v;
    __syncthreads();
    for (int off = 1; off < 256; off <<= 1) {
        int t = (tid >= off) ? s[tid - off] : 0;
        __syncthreads();
        s[tid] += t;
        __syncthreads();
    }
    if (i < N) rowptr[i] = s[tid] - v + bsum[blockIdx.x];
}

// ---------------- fill (CSR pairs) + weight conversion, one launch ----------
__device__ inline void convw_one(const float* W, unsigned short* hi, int FOUT, int id) {
    int n = id >> 7, k = id & 127;
    hi[id] = f2bf_rne(W[k * FOUT + n]);
}

__global__ __launch_bounds__(256) void fill_conv_k(
    const int* __restrict__ src, const int* __restrict__ dst,
    const float* __restrict__ dinv, int* __restrict__ rowptr,
    int2* __restrict__ pairs, int E, int fillBlocks,
    const float* __restrict__ W1, const float* __restrict__ W2,
    const float* __restrict__ W3,
    unsigned short* __restrict__ W1h, unsigned short* __restrict__ W2h,
    unsigned short* __restrict__ W3h) {
    if ((int)blockIdx.x < fillBlocks) {
        int e = blockIdx.x * 256 + threadIdx.x;
        if (e < E) {
            int s = src[e], d = dst[e];
            float nrm = dinv[s] * dinv[d];
            int pos = atomicAdd(&rowptr[d], 1);
            pairs[pos] = make_int2(s, __float_as_int(nrm));
        }
    } else {
        int id = (blockIdx.x - fillBlocks) * 256 + threadIdx.x;
        if (id < 16384) convw_one(W1, W1h, 128, id);
        else if (id < 32768) convw_one(W2, W2h, 128, id - 16384);
        else if (id < 40960) convw_one(W3, W3h, 64, id - 32768);
    }
}

// ---------------- MFMA GEMM: T[N][FOUT] = A[N][128] @ W[128][FOUT] ----------
// C = (Ah+Al)*Bh, fp32 acc. Block = 4 waves x 16 rows = 64 rows. Bh staged in
// LDS (R8). Epilogue: C hi+lo staged in same LDS (union), coalesced dwordx4
// copy-out. Layouts (m89): A[m=lane&15][k=quad*8+j], B = Wt[n=lane&15][k],
// C: col=lane&15, row=quad*4+reg.
__device__ inline void split8(const float* __restrict__ p, bf16x8& hi, bf16x8& lo) {
    float4 v0 = *(const float4*)p;
    float4 v1 = *(const float4*)(p + 4);
    float vv[8] = {v0.x, v0.y, v0.z, v0.w, v1.x, v1.y, v1.z, v1.w};
#pragma unroll
    for (int i = 0; i < 8; ++i) {
        unsigned short h = f2bf_rne(vv[i]);
        hi[i] = (short)h;
        lo[i] = (short)f2bf_rne(vv[i] - bf2f(h));
    }
}

template <int FOUT, bool AF32>
__global__ __launch_bounds__(256) void mfma_gemm(const float* __restrict__ Af,
                                                 const unsigned short* __restrict__ Ahi,
                                                 const unsigned short* __restrict__ Alo,
                                                 const unsigned short* __restrict__ Bhi,
                                                 unsigned short* __restrict__ Thi,
                                                 unsigned short* __restrict__ Tlo,
                                                 int N) {
    constexpr int NCT = FOUT / 16;
    constexpr int BSTRIDE = 136;          // B rows: 272B, 16B-aligned
    constexpr int CSTRIDE = FOUT + 8;     // 128->136 (272B), 64->72 (144B); 16B-aligned
    constexpr int CLOBASE = 64 * CSTRIDE; // lo tile offset (u16)
    constexpr int BU = FOUT * BSTRIDE;
    constexpr int CU = 2 * 64 * CSTRIDE;
    constexpr int SMEMU = (BU > CU) ? BU : CU;
    __shared__ unsigned short smem[SMEMU];

    const int tid = threadIdx.x;
    const int wv = tid >> 6, lane = tid & 63;
    const int quad = lane >> 4, l16 = lane & 15;
    const int row0 = blockIdx.x * 64 + wv * 16;

    // ---- stage Bh into LDS ----
#pragma unroll
    for (int it = 0; it < FOUT / 16; ++it) {
        int i = it * 256 + tid;
        int r = i >> 4, c = (i & 15) * 8;
        *(bf16x8*)(&smem[r * BSTRIDE + c]) = *(const bf16x8*)(Bhi + (size_t)r * 128 + c);
    }
    __syncthreads();

    f32x4 acc[NCT];
#pragma unroll
    for (int ct = 0; ct < NCT; ++ct)
        acc[ct] = (f32x4){0.f, 0.f, 0.f, 0.f};

    const int ra = AF32 ? min(row0 + l16, N - 1) : (row0 + l16);

#pragma unroll
    for (int ks = 0; ks < 4; ++ks) {
        const int ko = ks * 32 + quad * 8;
        bf16x8 ah, al;
        if (AF32) {
            split8(Af + (size_t)ra * 128 + ko, ah, al);
        } else {
            ah = *(const bf16x8*)(Ahi + (size_t)ra * 128 + ko);
            al = *(const bf16x8*)(Alo + (size_t)ra * 128 + ko);
        }
#pragma unroll
        for (int ct = 0; ct < NCT; ++ct) {
            bf16x8 bh = *(const bf16x8*)(&smem[(ct * 16 + l16) * BSTRIDE + ko]);
            acc[ct] = __builtin_amdgcn_mfma_f32_16x16x32_bf16(ah, bh, acc[ct], 0, 0, 0);
            acc[ct] = __builtin_amdgcn_mfma_f32_16x16x32_bf16(al, bh, acc[ct], 0, 0, 0);
        }
    }

    // ---- LDS-staged coalesced epilogue ----
    __syncthreads();  // all waves done reading B from smem
    const int lrow = wv * 16 + quad * 4;  // row within 64-row block (+ r)
#pragma unroll
    for (int ct = 0; ct < NCT; ++ct) {
        const int col = ct * 16 + l16;
#pragma unroll
        for (int r = 0; r < 4; ++r) {
            float v = acc[ct][r];
            unsigned short h = f2bf_rne(v);
            smem[(lrow + r) * CSTRIDE + col] = h;
            smem[CLOBASE + (lrow + r) * CSTRIDE + col] = f2bf_rne(v - bf2f(h));
        }
    }
    __syncthreads();
    constexpr int CH = FOUT / 8;  // 16B chunks per row
#pragma unroll
    for (int i = 0; i < 64 * CH / 256; ++i) {
        int ci = i * 256 + tid;
        int r = ci / CH, c = (ci % CH) * 8;  // c in u16 units
        int grow = blockIdx.x * 64 + r;
        if (grow < N) {
            *(uint4*)(Thi + (size_t)grow * FOUT + c) = *(const uint4*)&smem[r * CSTRIDE + c];
            *(uint4*)(Tlo + (size_t)grow * FOUT + c) = *(const uint4*)&smem[CLOBASE + r * CSTRIDE + c];
        }
    }
}

// ---------------- aggregation (R8 form): wave per row, no atomics ----------
// res[row] = b + (Thi+Tlo)[row]*dinv^2 + sum_e norm_e * Thi[src_e]
template <int FOUT, bool SPLIT>
__global__ __launch_bounds__(256) void gather_k(const int* __restrict__ rowend,
                                                const int2* __restrict__ pairs,
                                                const float* __restrict__ dinv,
                                                const unsigned short* __restrict__ Thi,
                                                const unsigned short* __restrict__ Tlo,
                                                const float* __restrict__ bias,
                                                float* __restrict__ out,
                                                unsigned short* __restrict__ outHi,
                                                unsigned short* __restrict__ outLo,
                                                int N) {
    const int wave = threadIdx.x >> 6;
    const int lane = threadIdx.x & 63;
    const int row = blockIdx.x * 4 + wave;
    if (row >= N) return;

    const int start = (row == 0) ? 0 : rowend[row - 1];
    const int end = rowend[row];
    const float dr = dinv[row];

    if (FOUT == 128) {
        const unsigned* thi32 = (const unsigned*)Thi;  // bf16x2 per dword
        const unsigned* tlo32 = (const unsigned*)Tlo;
        unsigned sh = thi32[(size_t)row * 64 + lane];
        unsigned sl = tlo32[(size_t)row * 64 + lane];
        float2 bb = *(const float2*)(bias + lane * 2);
        float ax = bb.x + (bf2f_lo(sh) + bf2f_lo(sl)) * dr * dr;
        float ay = bb.y + (bf2f_hi(sh) + bf2f_hi(sl)) * dr * dr;

        int j = start;
        if ((j & 1) && j < end) {
            int2 pv = pairs[j];
            unsigned m = thi32[(size_t)pv.x * 64 + lane];
            float n = __int_as_float(pv.y);
            ax += n * bf2f_lo(m);
            ay += n * bf2f_hi(m);
            ++j;
        }
        for (; j + 4 <= end; j += 4) {
            int4 p01 = *(const int4*)(pairs + j);
            int4 p23 = *(const int4*)(pairs + j + 2);
            unsigned m0 = thi32[(size_t)p01.x * 64 + lane];
            unsigned m1 = thi32[(size_t)p01.z * 64 + lane];
            unsigned m2 = thi32[(size_t)p23.x * 64 + lane];
            unsigned m3 = thi32[(size_t)p23.z * 64 + lane];
            float n0 = __int_as_float(p01.y), n1 = __int_as_float(p01.w);
            float n2 = __int_as_float(p23.y), n3 = __int_as_float(p23.w);
            ax += n0 * bf2f_lo(m0); ay += n0 * bf2f_hi(m0);
            ax += n1 * bf2f_lo(m1); ay += n1 * bf2f_hi(m1);
            ax += n2 * bf2f_lo(m2); ay += n2 * bf2f_hi(m2);
            ax += n3 * bf2f_lo(m3); ay += n3 * bf2f_hi(m3);
        }
        for (; j < end; ++j) {
            int2 pv = pairs[j];
            unsigned m = thi32[(size_t)pv.x * 64 + lane];
            float n = __int_as_float(pv.y);
            ax += n * bf2f_lo(m);
            ay += n * bf2f_hi(m);
        }

        if (SPLIT) {
            float vx = fmaxf(ax, 0.f), vy = fmaxf(ay, 0.f);
            ushort2 h, l;
            h.x = f2bf_rne(vx); l.x = f2bf_rne(vx - bf2f(h.x));
            h.y = f2bf_rne(vy); l.y = f2bf_rne(vy - bf2f(h.y));
            *(ushort2*)(outHi + (size_t)row * 128 + lane * 2) = h;
            *(ushort2*)(outLo + (size_t)row * 128 + lane * 2) = l;
        } else {
            float2 o; o.x = ax; o.y = ay;
            *(float2*)(out + (size_t)row * 128 + lane * 2) = o;
        }
    } else {
        float self = bf2f(Thi[(size_t)row * FOUT + lane]) + bf2f(Tlo[(size_t)row * FOUT + lane]);
        float acc = bias[lane] + self * dr * dr;

        int j = start;
        if ((j & 1) && j < end) {
            int2 pv = pairs[j];
            acc += __int_as_float(pv.y) * bf2f(Thi[(size_t)pv.x * FOUT + lane]);
            ++j;
        }
        for (; j + 4 <= end; j += 4) {
            int4 p01 = *(const int4*)(pairs + j);
            int4 p23 = *(const int4*)(pairs + j + 2);
            float m0 = bf2f(Thi[(size_t)p01.x * FOUT + lane]);
            float m1 = bf2f(Thi[(size_t)p01.z * FOUT + lane]);
            float m2 = bf2f(Thi[(size_t)p23.x * FOUT + lane]);
            float m3 = bf2f(Thi[(size_t)p23.z * FOUT + lane]);
            acc += __int_as_float(p01.y) * m0 + __int_as_float(p01.w) * m1 +
                   __int_as_float(p23.y) * m2 + __int_as_float(p23.w) * m3;
        }
        for (; j < end; ++j) {
            int2 pv = pairs[j];
            acc += __int_as_float(pv.y) * bf2f(Thi[(size_t)pv.x * FOUT + lane]);
        }
        out[(size_t)row * FOUT + lane] = acc;
    }
}

extern "C" void kernel_launch(void* const* d_in, const int* in_sizes, int n_in,
                              void* d_out, int out_size, void* d_ws, size_t ws_size,
                              hipStream_t stream) {
    const float* x  = (const float*)d_in[0];
    const int* eidx = (const int*)d_in[1];
    const float* W1 = (const float*)d_in[2];
    const float* b1 = (const float*)d_in[3];
    const float* W2 = (const float*)d_in[4];
    const float* b2 = (const float*)d_in[5];
    const float* W3 = (const float*)d_in[6];
    const float* b3 = (const float*)d_in[7];
    float* out = (float*)d_out;

    const int N = in_sizes[0] / IN_CH;
    const int E = in_sizes[1] / 2;
    const int* src = eidx;
    const int* dst = eidx + E;
    const int Npad = ((N + 127) / 128) * 128;
    const int nb = (N + 255) / 256;

    auto align = [](size_t v) { return (v + 255) / 256 * 256; };
    char* p = (char*)d_ws;
    int* cnt = (int*)p;            p += align((size_t)N * 4);
    int* rowptr = (int*)p;         p += align((size_t)N * 4);
    int* bsum = (int*)p;           p += align((size_t)nb * 4);
    float* dinv = (float*)p;       p += align((size_t)N * 4);
    int2* pairs = (int2*)p;        p += align((size_t)E * 8);
    unsigned short* Ahi = (unsigned short*)p;  p += align((size_t)Npad * 128 * 2);
    unsigned short* Alo = (unsigned short*)p;  p += align((size_t)Npad * 128 * 2);
    unsigned short* Thi = (unsigned short*)p;  p += align((size_t)Npad * 128 * 2);
    unsigned short* Tlo = (unsigned short*)p;  p += align((size_t)Npad * 128 * 2);
    unsigned short* W1h = (unsigned short*)p;  p += align(128 * 128 * 2);
    unsigned short* W2h = (unsigned short*)p;  p += align(128 * 128 * 2);
    unsigned short* W3h = (unsigned short*)p;

    // ---- CSR build (once; reused by all 3 layers) ----
    hipMemsetAsync(cnt, 0, (size_t)N * 4, stream);
    cnt_k<<<(E + 255) / 256, 256, 0, stream>>>(dst, cnt, E);
    scan1_k<<<nb, 256, 0, stream>>>(cnt, bsum, dinv, N);
    scan2_k<<<1, 512, 0, stream>>>(bsum, nb);
    scan3_k<<<nb, 256, 0, stream>>>(cnt, bsum, rowptr, N);
    const int fillBlocks = (E + 255) / 256;
    fill_conv_k<<<fillBlocks + 160, 256, 0, stream>>>(src, dst, dinv, rowptr, pairs,
                                                      E, fillBlocks, W1, W2, W3,
                                                      W1h, W2h, W3h);
    // rowptr[i] now holds END of row i.

    const int gemm_blocks = (N + 63) / 64;
    const int gather_blocks = (N + 3) / 4;

    // Layer 1 (A = x fp32, split in-register)
    mfma_gemm<128, true><<<gemm_blocks, 256, 0, stream>>>(x, nullptr, nullptr,
                                                          W1h, Thi, Tlo, N);
    gather_k<128, true><<<gather_blocks, 256, 0, stream>>>(rowptr, pairs, dinv, Thi, Tlo,
                                                           b1, nullptr, Ahi, Alo, N);
    // Layer 2
    mfma_gemm<128, false><<<gemm_blocks, 256, 0, stream>>>(nullptr, Ahi, Alo,
                                                           W2h, Thi, Tlo, N);
    gather_k<128, true><<<gather_blocks, 256, 0, stream>>>(rowptr, pairs, dinv, Thi, Tlo,
                                                           b2, nullptr, Ahi, Alo, N);
    // Layer 3
    mfma_gemm<64, false><<<gemm_blocks, 256, 0, stream>>>(nullptr, Ahi, Alo,
                                                          W3h, Thi, Tlo, N);
    gather_k<64, false><<<gather_blocks, 256, 0, stream>>>(rowptr, pairs, dinv, Thi, Tlo,
                                                           b3, out, nullptr, nullptr, N);
}

// Round 11
// 358.912 us; speedup vs baseline: 1.1094x; 1.0929x over previous
//
#include <hip/hip_runtime.h>

// GCN 3-layer forward on gfx950.
// Round 11: precision-budget arbitrage (absmax 0.0078 vs 0.0403 threshold).
//  - Drop Alo (A-residual): GEMM = Ah*Bh single MFMA pass (32 vs 64/wave),
//    A-stream bytes halve. Added error ~2.6e-3 std (eps*sigA*sigW*sqrt(K)).
//  - Drop Tlo (self-term residual): gemm writes hi only (25 vs 50 MB); error
//    2^-9*|T|*dinv^2, material only for ~34 isolated nodes.
// Gather stays R8-form (R9 lesson: random-256B transaction bound).

#define IN_CH 128

typedef __attribute__((ext_vector_type(8))) short bf16x8;
typedef __attribute__((ext_vector_type(4))) float f32x4;

__device__ inline unsigned short f2bf_rne(float f) {
    unsigned u = __float_as_uint(f);
    unsigned r = (u + 0x7FFFu + ((u >> 16) & 1u)) >> 16;
    return (unsigned short)r;
}
__device__ inline float bf2f(unsigned short h) {
    return __uint_as_float(((unsigned)h) << 16);
}
__device__ inline float bf2f_lo(unsigned m) {
    return __uint_as_float(m << 16);
}
__device__ inline float bf2f_hi(unsigned m) {
    return __uint_as_float(m & 0xffff0000u);
}

// ---------------- degree count ----------------
__global__ __launch_bounds__(256) void cnt_k(const int* __restrict__ dst,
                                             int* __restrict__ cnt, int E) {
    int e = blockIdx.x * 256 + threadIdx.x;
    if (e < E) atomicAdd(&cnt[dst[e]], 1);
}

// ---------------- scan stage 1 (+ dinv fused) ----------------
__global__ __launch_bounds__(256) void scan1_k(const int* __restrict__ cnt,
                                               int* __restrict__ bsum,
                                               float* __restrict__ dinv, int N) {
    __shared__ int s[256];
    int tid = threadIdx.x;
    int i = blockIdx.x * 256 + tid;
    int v = (i < N) ? cnt[i] : 0;
    if (i < N) dinv[i] = rsqrtf((float)v + 1.0f);
    s[tid] = v;
    __syncthreads();
    for (int off = 128; off > 0; off >>= 1) {
        if (tid < off) s[tid] += s[tid + off];
        __syncthreads();
    }
    if (tid == 0) bsum[blockIdx.x] = s[0];
}

__global__ __launch_bounds__(512) void scan2_k(int* __restrict__ bsum, int nb) {
    __shared__ int s[512];
    __shared__ int carry_s;
    int tid = threadIdx.x;
    if (tid == 0) carry_s = 0;
    __syncthreads();
    for (int base = 0; base < nb; base += 512) {
        int c = carry_s;
        int i = base + tid;
        int v = (i < nb) ? bsum[i] : 0;
        s[tid] = v;
        __syncthreads();
        for (int off = 1; off < 512; off <<= 1) {
            int t = (tid >= off) ? s[tid - off] : 0;
            __syncthreads();
            s[tid] += t;
            __syncthreads();
        }
        if (i < nb) bsum[i] = s[tid] - v + c;
        __syncthreads();
        if (tid == 0) carry_s = c + s[511];
        __syncthreads();
    }
}

__global__ __launch_bounds__(256) void scan3_k(const int* __restrict__ cnt,
                                               const int* __restrict__ bsum,
                                               int* __restrict__ rowptr, int N) {
    __shared__ int s[256];
    int tid = threadIdx.x;
    int i = blockIdx.x * 256 + tid;
    int v = (i < N) ? cnt[i] : 0;
    s[tid] = v;
    __syncthreads();
    for (int off = 1; off < 256; off <<= 1) {
        int t = (tid >= off) ? s[tid - off] : 0;
        __syncthreads();
        s[tid] += t;
        __syncthreads();
    }
    if (i < N) rowptr[i] = s[tid] - v + bsum[blockIdx.x];
}

// ---------------- fill (CSR pairs) + weight conversion, one launch ----------
__device__ inline void convw_one(const float* W, unsigned short* hi, int FOUT, int id) {
    int n = id >> 7, k = id & 127;
    hi[id] = f2bf_rne(W[k * FOUT + n]);
}

__global__ __launch_bounds__(256) void fill_conv_k(
    const int* __restrict__ src, const int* __restrict__ dst,
    const float* __restrict__ dinv, int* __restrict__ rowptr,
    int2* __restrict__ pairs, int E, int fillBlocks,
    const float* __restrict__ W1, const float* __restrict__ W2,
    const float* __restrict__ W3,
    unsigned short* __restrict__ W1h, unsigned short* __restrict__ W2h,
    unsigned short* __restrict__ W3h) {
    if ((int)blockIdx.x < fillBlocks) {
        int e = blockIdx.x * 256 + threadIdx.x;
        if (e < E) {
            int s = src[e], d = dst[e];
            float nrm = dinv[s] * dinv[d];
            int pos = atomicAdd(&rowptr[d], 1);
            pairs[pos] = make_int2(s, __float_as_int(nrm));
        }
    } else {
        int id = (blockIdx.x - fillBlocks) * 256 + threadIdx.x;
        if (id < 16384) convw_one(W1, W1h, 128, id);
        else if (id < 32768) convw_one(W2, W2h, 128, id - 16384);
        else if (id < 40960) convw_one(W3, W3h, 64, id - 32768);
    }
}

// ---------------- MFMA GEMM: T[N][FOUT] = A[N][128] @ W[128][FOUT] ----------
// C = Ah*Bh, fp32 acc, output bf16 hi only. Block = 4 waves x 16 rows.
// Bh staged in LDS (R8); LDS-staged coalesced epilogue (R10).
// Layouts (m89): A[m=lane&15][k=quad*8+j], B = Wt[n=lane&15][k],
// C: col=lane&15, row=quad*4+reg.
__device__ inline bf16x8 cvt8(const float* __restrict__ p) {
    float4 v0 = *(const float4*)p;
    float4 v1 = *(const float4*)(p + 4);
    bf16x8 h;
    h[0] = (short)f2bf_rne(v0.x); h[1] = (short)f2bf_rne(v0.y);
    h[2] = (short)f2bf_rne(v0.z); h[3] = (short)f2bf_rne(v0.w);
    h[4] = (short)f2bf_rne(v1.x); h[5] = (short)f2bf_rne(v1.y);
    h[6] = (short)f2bf_rne(v1.z); h[7] = (short)f2bf_rne(v1.w);
    return h;
}

template <int FOUT, bool AF32>
__global__ __launch_bounds__(256) void mfma_gemm(const float* __restrict__ Af,
                                                 const unsigned short* __restrict__ Ahi,
                                                 const unsigned short* __restrict__ Bhi,
                                                 unsigned short* __restrict__ Thi,
                                                 int N) {
    constexpr int NCT = FOUT / 16;
    constexpr int BSTRIDE = 136;          // B rows: 272B, 16B-aligned
    constexpr int CSTRIDE = FOUT + 8;     // C tile rows 16B-aligned, bank-spread
    constexpr int BU = FOUT * BSTRIDE;
    constexpr int CU = 64 * CSTRIDE;
    constexpr int SMEMU = (BU > CU) ? BU : CU;
    __shared__ unsigned short smem[SMEMU];

    const int tid = threadIdx.x;
    const int wv = tid >> 6, lane = tid & 63;
    const int quad = lane >> 4, l16 = lane & 15;
    const int row0 = blockIdx.x * 64 + wv * 16;

    // ---- stage Bh into LDS ----
#pragma unroll
    for (int it = 0; it < FOUT / 16; ++it) {
        int i = it * 256 + tid;
        int r = i >> 4, c = (i & 15) * 8;
        *(bf16x8*)(&smem[r * BSTRIDE + c]) = *(const bf16x8*)(Bhi + (size_t)r * 128 + c);
    }
    __syncthreads();

    f32x4 acc[NCT];
#pragma unroll
    for (int ct = 0; ct < NCT; ++ct)
        acc[ct] = (f32x4){0.f, 0.f, 0.f, 0.f};

    const int ra = AF32 ? min(row0 + l16, N - 1) : (row0 + l16);

#pragma unroll
    for (int ks = 0; ks < 4; ++ks) {
        const int ko = ks * 32 + quad * 8;
        bf16x8 ah;
        if (AF32) {
            ah = cvt8(Af + (size_t)ra * 128 + ko);
        } else {
            ah = *(const bf16x8*)(Ahi + (size_t)ra * 128 + ko);
        }
#pragma unroll
        for (int ct = 0; ct < NCT; ++ct) {
            bf16x8 bh = *(const bf16x8*)(&smem[(ct * 16 + l16) * BSTRIDE + ko]);
            acc[ct] = __builtin_amdgcn_mfma_f32_16x16x32_bf16(ah, bh, acc[ct], 0, 0, 0);
        }
    }

    // ---- LDS-staged coalesced epilogue (hi only) ----
    __syncthreads();
    const int lrow = wv * 16 + quad * 4;
#pragma unroll
    for (int ct = 0; ct < NCT; ++ct) {
        const int col = ct * 16 + l16;
#pragma unroll
        for (int r = 0; r < 4; ++r)
            smem[(lrow + r) * CSTRIDE + col] = f2bf_rne(acc[ct][r]);
    }
    __syncthreads();
    constexpr int CH = FOUT / 8;  // 16B chunks per row
#pragma unroll
    for (int i = 0; i < 64 * CH / 256; ++i) {
        int ci = i * 256 + tid;
        int r = ci / CH, c = (ci % CH) * 8;
        int grow = blockIdx.x * 64 + r;
        if (grow < N)
            *(uint4*)(Thi + (size_t)grow * FOUT + c) = *(const uint4*)&smem[r * CSTRIDE + c];
    }
}

// ---------------- aggregation (R8 form): wave per row, no atomics ----------
// res[row] = b + Thi[row]*dinv^2 + sum_e norm_e * Thi[src_e]
// SPLIT: write relu(res) as bf16 hi (next layer's A); else fp32 out.
template <int FOUT, bool SPLIT>
__global__ __launch_bounds__(256) void gather_k(const int* __restrict__ rowend,
                                                const int2* __restrict__ pairs,
                                                const float* __restrict__ dinv,
                                                const unsigned short* __restrict__ Thi,
                                                const float* __restrict__ bias,
                                                float* __restrict__ out,
                                                unsigned short* __restrict__ outHi,
                                                int N) {
    const int wave = threadIdx.x >> 6;
    const int lane = threadIdx.x & 63;
    const int row = blockIdx.x * 4 + wave;
    if (row >= N) return;

    const int start = (row == 0) ? 0 : rowend[row - 1];
    const int end = rowend[row];
    const float dr = dinv[row];

    if (FOUT == 128) {
        const unsigned* thi32 = (const unsigned*)Thi;  // bf16x2 per dword
        unsigned sh = thi32[(size_t)row * 64 + lane];
        float2 bb = *(const float2*)(bias + lane * 2);
        float ax = bb.x + bf2f_lo(sh) * dr * dr;
        float ay = bb.y + bf2f_hi(sh) * dr * dr;

        int j = start;
        if ((j & 1) && j < end) {
            int2 pv = pairs[j];
            unsigned m = thi32[(size_t)pv.x * 64 + lane];
            float n = __int_as_float(pv.y);
            ax += n * bf2f_lo(m);
            ay += n * bf2f_hi(m);
            ++j;
        }
        for (; j + 4 <= end; j += 4) {
            int4 p01 = *(const int4*)(pairs + j);
            int4 p23 = *(const int4*)(pairs + j + 2);
            unsigned m0 = thi32[(size_t)p01.x * 64 + lane];
            unsigned m1 = thi32[(size_t)p01.z * 64 + lane];
            unsigned m2 = thi32[(size_t)p23.x * 64 + lane];
            unsigned m3 = thi32[(size_t)p23.z * 64 + lane];
            float n0 = __int_as_float(p01.y), n1 = __int_as_float(p01.w);
            float n2 = __int_as_float(p23.y), n3 = __int_as_float(p23.w);
            ax += n0 * bf2f_lo(m0); ay += n0 * bf2f_hi(m0);
            ax += n1 * bf2f_lo(m1); ay += n1 * bf2f_hi(m1);
            ax += n2 * bf2f_lo(m2); ay += n2 * bf2f_hi(m2);
            ax += n3 * bf2f_lo(m3); ay += n3 * bf2f_hi(m3);
        }
        for (; j < end; ++j) {
            int2 pv = pairs[j];
            unsigned m = thi32[(size_t)pv.x * 64 + lane];
            float n = __int_as_float(pv.y);
            ax += n * bf2f_lo(m);
            ay += n * bf2f_hi(m);
        }

        if (SPLIT) {
            float vx = fmaxf(ax, 0.f), vy = fmaxf(ay, 0.f);
            ushort2 h;
            h.x = f2bf_rne(vx);
            h.y = f2bf_rne(vy);
            *(ushort2*)(outHi + (size_t)row * 128 + lane * 2) = h;
        } else {
            float2 o; o.x = ax; o.y = ay;
            *(float2*)(out + (size_t)row * 128 + lane * 2) = o;
        }
    } else {
        float acc = bias[lane] + bf2f(Thi[(size_t)row * FOUT + lane]) * dr * dr;

        int j = start;
        if ((j & 1) && j < end) {
            int2 pv = pairs[j];
            acc += __int_as_float(pv.y) * bf2f(Thi[(size_t)pv.x * FOUT + lane]);
            ++j;
        }
        for (; j + 4 <= end; j += 4) {
            int4 p01 = *(const int4*)(pairs + j);
            int4 p23 = *(const int4*)(pairs + j + 2);
            float m0 = bf2f(Thi[(size_t)p01.x * FOUT + lane]);
            float m1 = bf2f(Thi[(size_t)p01.z * FOUT + lane]);
            float m2 = bf2f(Thi[(size_t)p23.x * FOUT + lane]);
            float m3 = bf2f(Thi[(size_t)p23.z * FOUT + lane]);
            acc += __int_as_float(p01.y) * m0 + __int_as_float(p01.w) * m1 +
                   __int_as_float(p23.y) * m2 + __int_as_float(p23.w) * m3;
        }
        for (; j < end; ++j) {
            int2 pv = pairs[j];
            acc += __int_as_float(pv.y) * bf2f(Thi[(size_t)pv.x * FOUT + lane]);
        }
        out[(size_t)row * FOUT + lane] = acc;
    }
}

extern "C" void kernel_launch(void* const* d_in, const int* in_sizes, int n_in,
                              void* d_out, int out_size, void* d_ws, size_t ws_size,
                              hipStream_t stream) {
    const float* x  = (const float*)d_in[0];
    const int* eidx = (const int*)d_in[1];
    const float* W1 = (const float*)d_in[2];
    const float* b1 = (const float*)d_in[3];
    const float* W2 = (const float*)d_in[4];
    const float* b2 = (const float*)d_in[5];
    const float* W3 = (const float*)d_in[6];
    const float* b3 = (const float*)d_in[7];
    float* out = (float*)d_out;

    const int N = in_sizes[0] / IN_CH;
    const int E = in_sizes[1] / 2;
    const int* src = eidx;
    const int* dst = eidx + E;
    const int Npad = ((N + 127) / 128) * 128;
    const int nb = (N + 255) / 256;

    auto align = [](size_t v) { return (v + 255) / 256 * 256; };
    char* p = (char*)d_ws;
    int* cnt = (int*)p;            p += align((size_t)N * 4);
    int* rowptr = (int*)p;         p += align((size_t)N * 4);
    int* bsum = (int*)p;           p += align((size_t)nb * 4);
    float* dinv = (float*)p;       p += align((size_t)N * 4);
    int2* pairs = (int2*)p;        p += align((size_t)E * 8);
    unsigned short* Ahi = (unsigned short*)p;  p += align((size_t)Npad * 128 * 2);
    unsigned short* Thi = (unsigned short*)p;  p += align((size_t)Npad * 128 * 2);
    unsigned short* W1h = (unsigned short*)p;  p += align(128 * 128 * 2);
    unsigned short* W2h = (unsigned short*)p;  p += align(128 * 128 * 2);
    unsigned short* W3h = (unsigned short*)p;

    // ---- CSR build (once; reused by all 3 layers) ----
    hipMemsetAsync(cnt, 0, (size_t)N * 4, stream);
    cnt_k<<<(E + 255) / 256, 256, 0, stream>>>(dst, cnt, E);
    scan1_k<<<nb, 256, 0, stream>>>(cnt, bsum, dinv, N);
    scan2_k<<<1, 512, 0, stream>>>(bsum, nb);
    scan3_k<<<nb, 256, 0, stream>>>(cnt, bsum, rowptr, N);
    const int fillBlocks = (E + 255) / 256;
    fill_conv_k<<<fillBlocks + 160, 256, 0, stream>>>(src, dst, dinv, rowptr, pairs,
                                                      E, fillBlocks, W1, W2, W3,
                                                      W1h, W2h, W3h);
    // rowptr[i] now holds END of row i.

    const int gemm_blocks = (N + 63) / 64;
    const int gather_blocks = (N + 3) / 4;

    // Layer 1 (A = x fp32, converted in-register)
    mfma_gemm<128, true><<<gemm_blocks, 256, 0, stream>>>(x, nullptr, W1h, Thi, N);
    gather_k<128, true><<<gather_blocks, 256, 0, stream>>>(rowptr, pairs, dinv, Thi,
                                                           b1, nullptr, Ahi, N);
    // Layer 2
    mfma_gemm<128, false><<<gemm_blocks, 256, 0, stream>>>(nullptr, Ahi, W2h, Thi, N);
    gather_k<128, true><<<gather_blocks, 256, 0, stream>>>(rowptr, pairs, dinv, Thi,
                                                           b2, nullptr, Ahi, N);
    // Layer 3
    mfma_gemm<64, false><<<gemm_blocks, 256, 0, stream>>>(nullptr, Ahi, W3h, Thi, N);
    gather_k<64, false><<<gather_blocks, 256, 0, stream>>>(rowptr, pairs, dinv, Thi,
                                                           b3, out, nullptr, N);
}

// Round 12
// 342.397 us; speedup vs baseline: 1.1629x; 1.0482x over previous
//
#include <hip/hip_runtime.h>

// GCN 3-layer forward on gfx950.
// Round 12: gather de-overheaded further.
//  - pairs store BYTE offsets (src*256) -> no per-edge 64-bit addr mul.
//  - CSR rows padded to multiples of 4 with zero-norm pad edges (src offset 0,
//    L1-hot row 0): gather loop is branchless 4-unrolled only — no head peel,
//    no serial tail edges (~2/row previously latency-bound).
// GEMM unchanged (R11: single Ah*Bh pass, LDS B, LDS epilogue).

#define IN_CH 128

typedef __attribute__((ext_vector_type(8))) short bf16x8;
typedef __attribute__((ext_vector_type(4))) float f32x4;

__device__ inline unsigned short f2bf_rne(float f) {
    unsigned u = __float_as_uint(f);
    unsigned r = (u + 0x7FFFu + ((u >> 16) & 1u)) >> 16;
    return (unsigned short)r;
}
__device__ inline float bf2f(unsigned short h) {
    return __uint_as_float(((unsigned)h) << 16);
}
__device__ inline float bf2f_lo(unsigned m) {
    return __uint_as_float(m << 16);
}
__device__ inline float bf2f_hi(unsigned m) {
    return __uint_as_float(m & 0xffff0000u);
}

// ---------------- degree count ----------------
__global__ __launch_bounds__(256) void cnt_k(const int* __restrict__ dst,
                                             int* __restrict__ cnt, int E) {
    int e = blockIdx.x * 256 + threadIdx.x;
    if (e < E) atomicAdd(&cnt[dst[e]], 1);
}

// ---------------- scan stage 1 on PADDED counts (+ dinv from real) --------
__global__ __launch_bounds__(256) void scan1_k(const int* __restrict__ cnt,
                                               int* __restrict__ bsum,
                                               float* __restrict__ dinv, int N) {
    __shared__ int s[256];
    int tid = threadIdx.x;
    int i = blockIdx.x * 256 + tid;
    int vr = (i < N) ? cnt[i] : 0;
    if (i < N) dinv[i] = rsqrtf((float)vr + 1.0f);
    s[tid] = (i < N) ? ((vr + 3) & ~3) : 0;  // padded count
    __syncthreads();
    for (int off = 128; off > 0; off >>= 1) {
        if (tid < off) s[tid] += s[tid + off];
        __syncthreads();
    }
    if (tid == 0) bsum[blockIdx.x] = s[0];
}

__global__ __launch_bounds__(512) void scan2_k(int* __restrict__ bsum, int nb) {
    __shared__ int s[512];
    __shared__ int carry_s;
    int tid = threadIdx.x;
    if (tid == 0) carry_s = 0;
    __syncthreads();
    for (int base = 0; base < nb; base += 512) {
        int c = carry_s;
        int i = base + tid;
        int v = (i < nb) ? bsum[i] : 0;
        s[tid] = v;
        __syncthreads();
        for (int off = 1; off < 512; off <<= 1) {
            int t = (tid >= off) ? s[tid - off] : 0;
            __syncthreads();
            s[tid] += t;
            __syncthreads();
        }
        if (i < nb) bsum[i] = s[tid] - v + c;
        __syncthreads();
        if (tid == 0) carry_s = c + s[511];
        __syncthreads();
    }
}

// scan3: padded exclusive scan -> rowstart[N+1] (preserved) + cur[N] (cursor)
__global__ __launch_bounds__(256) void scan3_k(const int* __restrict__ cnt,
                                               const int* __restrict__ bsum,
                                               int* __restrict__ rowstart,
                                               int* __restrict__ cur, int N) {
    __shared__ int s[256];
    int tid = threadIdx.x;
    int i = blockIdx.x * 256 + tid;
    int v = (i < N) ? ((cnt[i] + 3) & ~3) : 0;
    s[tid] = v;
    __syncthreads();
    for (int off = 1; off < 256; off <<= 1) {
        int t = (tid >= off) ? s[tid - off] : 0;
        __syncthreads();
        s[tid] += t;
        __syncthreads();
    }
    if (i < N) {
        int st = s[tid] - v + bsum[blockIdx.x];
        rowstart[i] = st;
        cur[i] = st;
        if (i == N - 1) rowstart[N] = st + v;
    }
}

// ---------------- fill (CSR pairs, byte offsets) + W conversion ------------
__device__ inline void convw_one(const float* W, unsigned short* hi, int FOUT, int id) {
    int n = id >> 7, k = id & 127;
    hi[id] = f2bf_rne(W[k * FOUT + n]);
}

__global__ __launch_bounds__(256) void fill_conv_k(
    const int* __restrict__ src, const int* __restrict__ dst,
    const float* __restrict__ dinv, int* __restrict__ cur,
    int2* __restrict__ pairs, int E, int fillBlocks,
    const float* __restrict__ W1, const float* __restrict__ W2,
    const float* __restrict__ W3,
    unsigned short* __restrict__ W1h, unsigned short* __restrict__ W2h,
    unsigned short* __restrict__ W3h) {
    if ((int)blockIdx.x < fillBlocks) {
        int e = blockIdx.x * 256 + threadIdx.x;
        if (e < E) {
            int s = src[e], d = dst[e];
            float nrm = dinv[s] * dinv[d];
            int pos = atomicAdd(&cur[d], 1);
            pairs[pos] = make_int2(s * 256, __float_as_int(nrm));  // byte offset
        }
    } else {
        int id = (blockIdx.x - fillBlocks) * 256 + threadIdx.x;
        if (id < 16384) convw_one(W1, W1h, 128, id);
        else if (id < 32768) convw_one(W2, W2h, 128, id - 16384);
        else if (id < 40960) convw_one(W3, W3h, 64, id - 32768);
    }
}

// ---------------- MFMA GEMM: T[N][FOUT] = A[N][128] @ W[128][FOUT] ----------
// C = Ah*Bh, fp32 acc, output bf16 hi only. Block = 4 waves x 16 rows.
// Bh staged in LDS (R8); LDS-staged coalesced epilogue (R10).
__device__ inline bf16x8 cvt8(const float* __restrict__ p) {
    float4 v0 = *(const float4*)p;
    float4 v1 = *(const float4*)(p + 4);
    bf16x8 h;
    h[0] = (short)f2bf_rne(v0.x); h[1] = (short)f2bf_rne(v0.y);
    h[2] = (short)f2bf_rne(v0.z); h[3] = (short)f2bf_rne(v0.w);
    h[4] = (short)f2bf_rne(v1.x); h[5] = (short)f2bf_rne(v1.y);
    h[6] = (short)f2bf_rne(v1.z); h[7] = (short)f2bf_rne(v1.w);
    return h;
}

template <int FOUT, bool AF32>
__global__ __launch_bounds__(256) void mfma_gemm(const float* __restrict__ Af,
                                                 const unsigned short* __restrict__ Ahi,
                                                 const unsigned short* __restrict__ Bhi,
                                                 unsigned short* __restrict__ Thi,
                                                 int N) {
    constexpr int NCT = FOUT / 16;
    constexpr int BSTRIDE = 136;
    constexpr int CSTRIDE = FOUT + 8;
    constexpr int BU = FOUT * BSTRIDE;
    constexpr int CU = 64 * CSTRIDE;
    constexpr int SMEMU = (BU > CU) ? BU : CU;
    __shared__ unsigned short smem[SMEMU];

    const int tid = threadIdx.x;
    const int wv = tid >> 6, lane = tid & 63;
    const int quad = lane >> 4, l16 = lane & 15;
    const int row0 = blockIdx.x * 64 + wv * 16;

#pragma unroll
    for (int it = 0; it < FOUT / 16; ++it) {
        int i = it * 256 + tid;
        int r = i >> 4, c = (i & 15) * 8;
        *(bf16x8*)(&smem[r * BSTRIDE + c]) = *(const bf16x8*)(Bhi + (size_t)r * 128 + c);
    }
    __syncthreads();

    f32x4 acc[NCT];
#pragma unroll
    for (int ct = 0; ct < NCT; ++ct)
        acc[ct] = (f32x4){0.f, 0.f, 0.f, 0.f};

    const int ra = AF32 ? min(row0 + l16, N - 1) : (row0 + l16);

#pragma unroll
    for (int ks = 0; ks < 4; ++ks) {
        const int ko = ks * 32 + quad * 8;
        bf16x8 ah;
        if (AF32) {
            ah = cvt8(Af + (size_t)ra * 128 + ko);
        } else {
            ah = *(const bf16x8*)(Ahi + (size_t)ra * 128 + ko);
        }
#pragma unroll
        for (int ct = 0; ct < NCT; ++ct) {
            bf16x8 bh = *(const bf16x8*)(&smem[(ct * 16 + l16) * BSTRIDE + ko]);
            acc[ct] = __builtin_amdgcn_mfma_f32_16x16x32_bf16(ah, bh, acc[ct], 0, 0, 0);
        }
    }

    __syncthreads();
    const int lrow = wv * 16 + quad * 4;
#pragma unroll
    for (int ct = 0; ct < NCT; ++ct) {
        const int col = ct * 16 + l16;
#pragma unroll
        for (int r = 0; r < 4; ++r)
            smem[(lrow + r) * CSTRIDE + col] = f2bf_rne(acc[ct][r]);
    }
    __syncthreads();
    constexpr int CH = FOUT / 8;
#pragma unroll
    for (int i = 0; i < 64 * CH / 256; ++i) {
        int ci = i * 256 + tid;
        int r = ci / CH, c = (ci % CH) * 8;
        int grow = blockIdx.x * 64 + r;
        if (grow < N)
            *(uint4*)(Thi + (size_t)grow * FOUT + c) = *(const uint4*)&smem[r * CSTRIDE + c];
    }
}

// ---------------- aggregation: wave per row, branchless 4-unrolled ---------
// res[row] = b + Thi[row]*dinv^2 + sum_e norm_e * Thi@off_e
// Rows padded to 4-multiples with (off=0, norm=0) pad edges.
template <int FOUT, bool SPLIT>
__global__ __launch_bounds__(256) void gather_k(const int* __restrict__ rowstart,
                                                const int2* __restrict__ pairs,
                                                const float* __restrict__ dinv,
                                                const unsigned short* __restrict__ Thi,
                                                const float* __restrict__ bias,
                                                float* __restrict__ out,
                                                unsigned short* __restrict__ outHi,
                                                int N) {
    const int wave = threadIdx.x >> 6;
    const int lane = threadIdx.x & 63;
    const int row = blockIdx.x * 4 + wave;
    if (row >= N) return;

    const int start = rowstart[row];
    const int end = rowstart[row + 1];
    const float dr = dinv[row];
    const char* tbase = (const char*)Thi;

    if (FOUT == 128) {
        const int laneB = lane * 4;  // dword per lane
        unsigned sh = *(const unsigned*)(tbase + (size_t)row * 256 + laneB);
        float2 bb = *(const float2*)(bias + lane * 2);
        float ax = bb.x + bf2f_lo(sh) * dr * dr;
        float ay = bb.y + bf2f_hi(sh) * dr * dr;

        for (int j = start; j < end; j += 4) {
            int4 p01 = *(const int4*)(pairs + j);
            int4 p23 = *(const int4*)(pairs + j + 2);
            unsigned m0 = *(const unsigned*)(tbase + (unsigned)p01.x + laneB);
            unsigned m1 = *(const unsigned*)(tbase + (unsigned)p01.z + laneB);
            unsigned m2 = *(const unsigned*)(tbase + (unsigned)p23.x + laneB);
            unsigned m3 = *(const unsigned*)(tbase + (unsigned)p23.z + laneB);
            float n0 = __int_as_float(p01.y), n1 = __int_as_float(p01.w);
            float n2 = __int_as_float(p23.y), n3 = __int_as_float(p23.w);
            ax += n0 * bf2f_lo(m0); ay += n0 * bf2f_hi(m0);
            ax += n1 * bf2f_lo(m1); ay += n1 * bf2f_hi(m1);
            ax += n2 * bf2f_lo(m2); ay += n2 * bf2f_hi(m2);
            ax += n3 * bf2f_lo(m3); ay += n3 * bf2f_hi(m3);
        }

        if (SPLIT) {
            float vx = fmaxf(ax, 0.f), vy = fmaxf(ay, 0.f);
            ushort2 h;
            h.x = f2bf_rne(vx);
            h.y = f2bf_rne(vy);
            *(ushort2*)(outHi + (size_t)row * 128 + lane * 2) = h;
        } else {
            float2 o; o.x = ax; o.y = ay;
            *(float2*)(out + (size_t)row * 128 + lane * 2) = o;
        }
    } else {  // FOUT == 64: rows are 128B; byte offset = off>>1; ushort per lane
        const int laneB = lane * 2;
        float acc = bias[lane] +
                    bf2f(*(const unsigned short*)(tbase + (size_t)row * 128 + laneB)) * dr * dr;

        for (int j = start; j < end; j += 4) {
            int4 p01 = *(const int4*)(pairs + j);
            int4 p23 = *(const int4*)(pairs + j + 2);
            float m0 = bf2f(*(const unsigned short*)(tbase + ((unsigned)p01.x >> 1) + laneB));
            float m1 = bf2f(*(const unsigned short*)(tbase + ((unsigned)p01.z >> 1) + laneB));
            float m2 = bf2f(*(const unsigned short*)(tbase + ((unsigned)p23.x >> 1) + laneB));
            float m3 = bf2f(*(const unsigned short*)(tbase + ((unsigned)p23.z >> 1) + laneB));
            acc += __int_as_float(p01.y) * m0 + __int_as_float(p01.w) * m1 +
                   __int_as_float(p23.y) * m2 + __int_as_float(p23.w) * m3;
        }
        out[(size_t)row * FOUT + lane] = acc;
    }
}

extern "C" void kernel_launch(void* const* d_in, const int* in_sizes, int n_in,
                              void* d_out, int out_size, void* d_ws, size_t ws_size,
                              hipStream_t stream) {
    const float* x  = (const float*)d_in[0];
    const int* eidx = (const int*)d_in[1];
    const float* W1 = (const float*)d_in[2];
    const float* b1 = (const float*)d_in[3];
    const float* W2 = (const float*)d_in[4];
    const float* b2 = (const float*)d_in[5];
    const float* W3 = (const float*)d_in[6];
    const float* b3 = (const float*)d_in[7];
    float* out = (float*)d_out;

    const int N = in_sizes[0] / IN_CH;
    const int E = in_sizes[1] / 2;
    const int* src = eidx;
    const int* dst = eidx + E;
    const int Npad = ((N + 127) / 128) * 128;
    const int nb = (N + 255) / 256;
    const int Emax = E + 3 * N;  // padded-pairs upper bound

    auto align = [](size_t v) { return (v + 255) / 256 * 256; };
    char* p = (char*)d_ws;
    int* cnt = (int*)p;            p += align((size_t)N * 4);
    int* rowstart = (int*)p;       p += align((size_t)(N + 1) * 4);
    int* cur = (int*)p;            p += align((size_t)N * 4);
    int* bsum = (int*)p;           p += align((size_t)nb * 4);
    float* dinv = (float*)p;       p += align((size_t)N * 4);
    int2* pairs = (int2*)p;        p += align((size_t)Emax * 8);
    unsigned short* Ahi = (unsigned short*)p;  p += align((size_t)Npad * 128 * 2);
    unsigned short* Thi = (unsigned short*)p;  p += align((size_t)Npad * 128 * 2);
    unsigned short* W1h = (unsigned short*)p;  p += align(128 * 128 * 2);
    unsigned short* W2h = (unsigned short*)p;  p += align(128 * 128 * 2);
    unsigned short* W3h = (unsigned short*)p;

    // ---- CSR build (once; reused by all 3 layers) ----
    hipMemsetAsync(cnt, 0, (size_t)N * 4, stream);
    hipMemsetAsync(pairs, 0, (size_t)Emax * 8, stream);  // pad edges = (0,0)
    cnt_k<<<(E + 255) / 256, 256, 0, stream>>>(dst, cnt, E);
    scan1_k<<<nb, 256, 0, stream>>>(cnt, bsum, dinv, N);
    scan2_k<<<1, 512, 0, stream>>>(bsum, nb);
    scan3_k<<<nb, 256, 0, stream>>>(cnt, bsum, rowstart, cur, N);
    const int fillBlocks = (E + 255) / 256;
    fill_conv_k<<<fillBlocks + 160, 256, 0, stream>>>(src, dst, dinv, cur, pairs,
                                                      E, fillBlocks, W1, W2, W3,
                                                      W1h, W2h, W3h);

    const int gemm_blocks = (N + 63) / 64;
    const int gather_blocks = (N + 3) / 4;

    // Layer 1 (A = x fp32, converted in-register)
    mfma_gemm<128, true><<<gemm_blocks, 256, 0, stream>>>(x, nullptr, W1h, Thi, N);
    gather_k<128, true><<<gather_blocks, 256, 0, stream>>>(rowstart, pairs, dinv, Thi,
                                                           b1, nullptr, Ahi, N);
    // Layer 2
    mfma_gemm<128, false><<<gemm_blocks, 256, 0, stream>>>(nullptr, Ahi, W2h, Thi, N);
    gather_k<128, true><<<gather_blocks, 256, 0, stream>>>(rowstart, pairs, dinv, Thi,
                                                           b2, nullptr, Ahi, N);
    // Layer 3
    mfma_gemm<64, false><<<gemm_blocks, 256, 0, stream>>>(nullptr, Ahi, W3h, Thi, N);
    gather_k<64, false><<<gather_blocks, 256, 0, stream>>>(rowstart, pairs, dinv, Thi,
                                                           b3, out, nullptr, N);
}